// Round 4
// baseline (82.120 us; speedup 1.0000x reference)
//
#include <hip/hip_runtime.h>
#include <math.h>

#define GDIM 640
#define NDIM 320
#define NB 8
#define NM 200000
#define KROWS 643            // padded kbuf rows: logical kx = -1 .. 641
#define KSTRIDE 644          // padded kbuf row stride (16B-aligned, cols -1..641 + pad)
#define PI_F 3.14159265358979323846f

// ---------- Bessel I0 (Abramowitz & Stegun 9.8.1/9.8.2, |err| < 2e-7) ----------
__device__ __forceinline__ float bessel_i0f(float x) {
    if (x < 3.75f) {
        float t = x * (1.0f / 3.75f);
        t *= t;
        return 1.0f + t * (3.5156229f + t * (3.0899424f + t * (1.2067492f +
                     t * (0.2659732f + t * (0.0360768f + t * 0.0045813f)))));
    }
    float t = 3.75f / x;
    float p = 0.39894228f + t * (0.01328592f + t * (0.00225319f + t * (-0.00157565f +
              t * (0.00916281f + t * (-0.02057706f + t * (0.02635537f +
              t * (-0.01647633f + t * 0.00392377f)))))));
    return p * __expf(x) * rsqrtf(x);
}

// ---------- deapodization 1/c helper ----------
__device__ __forceinline__ float deapod_c(int i, float beta2) {
    float xs = (float)(i - NDIM / 2) * (1.0f / (float)GDIM);
    float p = PI_F * 3.0f * xs;
    float arg = beta2 - p * p;
    float s = sqrtf(fabsf(arg));
    if (arg > 0.0f) return sinhf(s) / s;
    return (s < 1e-12f) ? 1.0f : sinf(s) / s;   // not reached for these params
}

// ---------- Kaiser-Bessel kernel weight ----------
__device__ __forceinline__ float kbw(float d, float beta) {
    if (fabsf(d) > 1.5f) return 0.0f;
    float u = d * (2.0f / 3.0f);
    float t = 1.0f - u * u;
    t = fmaxf(t, 0.0f);
    return bessel_i0f(beta * sqrtf(t));
}

// ---------- build twiddle table: tw[i] = exp(-2*pi*i*I/640), i = 0..639 ----------
__device__ __forceinline__ void build_tw(float2* tw, int tid) {
    for (int i = tid; i < 640; i += 320) {
        float sw, cw;
        __sincosf(-2.0f * PI_F * (float)i * (1.0f / 640.0f), &sw, &cw);
        tw[i] = make_float2(cw, sw);
    }
}

// ---------- 640-point FFT in LDS: 640 = 5 x 128, table twiddles ----------
// Input : lds[n], natural order. Output: lds[ks], fftshifted spectrum.
// blockDim.x == 320. Caller must __syncthreads() after.
__device__ __forceinline__ void fft640_core(float2* lds, float2* lds2,
                                            const float2* tw, int tid) {
    // --- radix-5 stage + inter-stage twiddle: threads 0..127 ---
    if (tid < 128) {
        const int bb = tid;
        float2 xa[5];
#pragma unroll
        for (int a = 0; a < 5; ++a) xa[a] = lds[a * 128 + bb];
        const float c5[5] = {1.0f, 0.30901699f, -0.80901699f, -0.80901699f, 0.30901699f};
        const float s5[5] = {0.0f, -0.95105652f, -0.58778525f, 0.58778525f, 0.95105652f};
#pragma unroll
        for (int k1 = 0; k1 < 5; ++k1) {
            float2 acc = xa[0];
#pragma unroll
            for (int a = 1; a < 5; ++a) {
                int j = (a * k1) % 5;
                acc.x += xa[a].x * c5[j] - xa[a].y * s5[j];
                acc.y += xa[a].x * s5[j] + xa[a].y * c5[j];
            }
            float2 w = tw[bb * k1];          // bb*k1 <= 508 < 640
            float2 r;
            r.x = acc.x * w.x - acc.y * w.y;
            r.y = acc.x * w.y + acc.y * w.x;
            lds2[k1 * 128 + bb] = r;
        }
    }
    __syncthreads();

    // --- 5 independent 128-point radix-2 DIF FFTs ---
    const int f = tid >> 6;
    const int j = tid & 63;
    float2* arr = lds2 + f * 128;
#pragma unroll
    for (int h = 64; h >= 1; h >>= 1) {
        int g = j / h;
        int jj = j - g * h;
        int p = g * 2 * h + jj;
        float2 u = arr[p];
        float2 v = arr[p + h];
        float2 s = make_float2(u.x + v.x, u.y + v.y);
        float2 d = make_float2(u.x - v.x, u.y - v.y);
        float2 w = tw[jj * (320 / h)];       // exp(-i*pi*jj/h), idx < 320
        arr[p] = s;
        arr[p + h] = make_float2(d.x * w.x - d.y * w.y, d.x * w.y + d.y * w.x);
        __syncthreads();
    }

    // --- un-bit-reverse + composite reorder + fftshift ---
#pragma unroll
    for (int half = 0; half < 2; ++half) {
        int k2 = j + 64 * half;
        int src = f * 128 + (int)(__brev((unsigned)k2) >> 25);
        int k = f + 5 * k2;
        int ks = (k >= 320) ? (k - 320) : (k + 320);
        lds[ks] = lds2[src];
    }
}

// ---------- Pass A: deapod + pad + ifftshift + FFT over x (non-zero rows only) ----------
// Compact storage: buf1c[b][r][kxs], r = 0..319 <-> ifftshifted row y = (r<160)? r : r+320.
__global__ __launch_bounds__(320) void pass_a(const float* __restrict__ x_re,
                                              const float* __restrict__ x_im,
                                              float2* __restrict__ buf1c,
                                              float beta2) {
    __shared__ float2 lds[640];
    __shared__ float2 lds2[640];
    __shared__ float2 tw[640];
    const int b = blockIdx.y;
    const int r = blockIdx.x;          // compact row 0..319
    const int tid = threadIdx.x;

    build_tw(tw, tid);

    const int ry = (r < 160) ? (r + 160) : (r - 160);   // source image row 0..319
    const float cy = deapod_c(ry, beta2);
    const float scale = 1.0f / (cy * (float)GDIM);

    for (int i = tid; i < GDIM; i += 320) {
        int xx = (i >= 320) ? (i - 320) : (i + 320);
        float2 v = make_float2(0.0f, 0.0f);
        if (xx >= 160 && xx < 480) {
            int rx = xx - 160;
            float cx = deapod_c(rx, beta2);
            float sc = scale / cx;
            size_t off = ((size_t)b * NDIM + ry) * NDIM + rx;
            v.x = x_re[off] * sc;
            v.y = x_im[off] * sc;
        }
        lds[i] = v;
    }
    __syncthreads();

    fft640_core(lds, lds2, tw, tid);
    __syncthreads();

    float2* dst = buf1c + ((size_t)b * NDIM + r) * GDIM;
    for (int i = tid; i < GDIM; i += 320) dst[i] = lds[i];
}

// ---------- Pass B: FFT over y, 4 columns per block, padded+halo output ----------
// kbuf physical layout [b][pr][pc], pr = kx+1 (rows -1..641), pc = ky+1 (cols -1..641),
// stride KSTRIDE. Halos duplicate wrap values so gather needs no modulo.
__global__ __launch_bounds__(320) void pass_b(const float2* __restrict__ buf1c,
                                              float2* __restrict__ kbuf) {
    __shared__ float2 colsT[4][648];   // stride 648 to spread banks
    __shared__ float2 lds2[640];
    __shared__ float2 tw[640];
    const int b = blockIdx.y;
    const int kxs0 = blockIdx.x * 4;
    const int tid = threadIdx.x;

    build_tw(tw, tid);

    // coalesced load: thread (r = t>>2, c = t&3) reads 32B-contiguous groups
    for (int base = 0; base < NDIM; base += 80) {
        int r = base + (tid >> 2);
        int c = tid & 3;
        float2 v = buf1c[((size_t)b * NDIM + r) * GDIM + kxs0 + c];
        int y = (r < 160) ? r : (r + 320);       // compact -> ifftshifted y
        colsT[c][y] = v;
    }
    // zero the padded middle y = 160..479 (4 cols x 320)
    for (int i = tid; i < 1280; i += 320) {
        colsT[i & 3][160 + (i >> 2)] = make_float2(0.0f, 0.0f);
    }
    __syncthreads();

    float2* kbb = kbuf + (size_t)b * KROWS * KSTRIDE;

#pragma unroll
    for (int c = 0; c < 4; ++c) {
        fft640_core(&colsT[c][0], lds2, tw, tid);
        __syncthreads();

        const int kxs = kxs0 + c;
        // main row pr = kxs+1, plus halo duplicates
        int prs[2];
        int nduprow = 1;
        prs[0] = kxs + 1;
        if (kxs == 639) { prs[1] = 0;   nduprow = 2; }
        if (kxs == 0)   { prs[1] = 641; nduprow = 2; }
        if (kxs == 1)   { prs[1] = 642; nduprow = 2; }
        for (int rr = 0; rr < nduprow; ++rr) {
            float2* dst = kbb + (size_t)prs[rr] * KSTRIDE;
            for (int i = tid; i < GDIM; i += 320) dst[1 + i] = colsT[c][i];
            if (tid == 0) {
                dst[0]   = colsT[c][639];   // col -1  = wrap of ky 639
                dst[641] = colsT[c][0];     // col 640 = wrap of ky 0
                dst[642] = colsT[c][1];     // col 641 = wrap of ky 1
            }
        }
        __syncthreads();   // protect lds2 before next column's FFT
    }
}

// ---------- Gather: 3x3 KB interpolation + sqrt(dcf), 1 sample/thread ----------
// Block -> XCD partitioning: b = blockIdx.x & 7 so each XCD's L2 caches only
// its own batch's kbuf slice (3.3 MB < 4 MB L2).
// Padded kbuf: no wrap handling; 3 ky taps covered by 2 aligned float4 loads.
#define GBLK_PER_B ((NM + 255) / 256)      // 782
__global__ __launch_bounds__(256) void gather_kernel(const float* __restrict__ traj,
                                                     const float* __restrict__ dcf,
                                                     const float2* __restrict__ kbuf,
                                                     float2* __restrict__ out,
                                                     float beta) {
    const int bid = blockIdx.x;
    const int b = bid & 7;
    const int m = (bid >> 3) * 256 + threadIdx.x;
    if (m >= NM) return;

    const float tx = traj[((size_t)b * 2 + 0) * NM + m];
    const float ty = traj[((size_t)b * 2 + 1) * NM + m];
    const float cx = (tx + 0.5f) * (float)GDIM;
    const float cy = (ty + 0.5f) * (float)GDIM;
    const int bxi = (int)floorf(cx - 1.0f);   // -1 .. 639
    const int byi = (int)floorf(cy - 1.0f);
    const float fx = cx - (float)bxi;         // d at tap 0, in [1,2)
    const float fy = cy - (float)byi;

    const float2* __restrict__ kb = kbuf + (size_t)b * KROWS * KSTRIDE;
    const int pc0 = byi + 1;                  // 0..640
    const int odd = pc0 & 1;

    // issue all 6 aligned 16B loads first
    float4 A[3], Bv[3];
#pragma unroll
    for (int lx = 0; lx < 3; ++lx) {
        size_t e = ((size_t)(bxi + 1 + lx) * KSTRIDE + (size_t)pc0) & ~(size_t)1;
        const float4* p = (const float4*)(kb + e);
        A[lx] = p[0];
        Bv[lx] = p[1];
    }

    // weights while loads are in flight
    float wx[3], wy[3];
#pragma unroll
    for (int l = 0; l < 3; ++l) {
        wx[l] = kbw(fx - (float)l, beta);
        wy[l] = kbw(fy - (float)l, beta);
    }

    float accx = 0.0f, accy = 0.0f;
#pragma unroll
    for (int lx = 0; lx < 3; ++lx) {
        float t0x = odd ? A[lx].z : A[lx].x;
        float t0y = odd ? A[lx].w : A[lx].y;
        float t1x = odd ? Bv[lx].x : A[lx].z;
        float t1y = odd ? Bv[lx].y : A[lx].w;
        float t2x = odd ? Bv[lx].z : Bv[lx].x;
        float t2y = odd ? Bv[lx].w : Bv[lx].y;
        const float w0 = wx[lx] * wy[0];
        const float w1 = wx[lx] * wy[1];
        const float w2 = wx[lx] * wy[2];
        accx += t0x * w0 + t1x * w1 + t2x * w2;
        accy += t0y * w0 + t1y * w1 + t2y * w2;
    }
    const float s = sqrtf(dcf[(size_t)b * NM + m]);
    out[(size_t)b * NM + m] = make_float2(accx * s, accy * s);
}

extern "C" void kernel_launch(void* const* d_in, const int* in_sizes, int n_in,
                              void* d_out, int out_size, void* d_ws, size_t ws_size,
                              hipStream_t stream) {
    const float* x_re = (const float*)d_in[0];
    const float* x_im = (const float*)d_in[1];
    const float* traj = (const float*)d_in[2];
    const float* dcf  = (const float*)d_in[3];

    float2* buf1c = (float2*)d_ws;                          // [B][320][640] row-FFT (non-zero rows)
    float2* kbuf  = buf1c + (size_t)NB * NDIM * GDIM;       // [B][643][644] padded kgrid^T

    const double beta_d = M_PI * sqrt((1.5 * 1.5) * (1.5 * 1.5) - 0.8);
    const float beta = (float)beta_d;
    const float beta2 = (float)(beta_d * beta_d);

    dim3 gridA(NDIM, NB);
    pass_a<<<gridA, 320, 0, stream>>>(x_re, x_im, buf1c, beta2);

    dim3 gridB(GDIM / 4, NB);
    pass_b<<<gridB, 320, 0, stream>>>(buf1c, kbuf);

    gather_kernel<<<GBLK_PER_B * NB, 256, 0, stream>>>(traj, dcf, kbuf,
                                                       (float2*)d_out, beta);
}